// Round 7
// baseline (198.195 us; speedup 1.0000x reference)
//
#include <hip/hip_runtime.h>
#include <hip/hip_fp16.h>
#include <cmath>

typedef _Float16 f16;
typedef __attribute__((ext_vector_type(8))) _Float16 f16x8;
typedef __attribute__((ext_vector_type(4))) _Float16 f16x4;
typedef __attribute__((ext_vector_type(4))) float f32x4;

// async 16B global->LDS (per-lane global addr; LDS dest = base + lane*16)
typedef __attribute__((address_space(3))) unsigned int lds_u32;
typedef const __attribute__((address_space(1))) unsigned int g_u32;
__device__ __forceinline__ void async_copy16(const void* g, void* l) {
    __builtin_amdgcn_global_load_lds((g_u32*)g, (lds_u32*)l, 16, 0, 0);
}

#define EXP2F(x) __builtin_amdgcn_exp2f(x)

// ---------------------------------------------------------------------------
// fused f32 -> f16 cast over 3 segments (x, qkv_w, proj_w), 4 elems/thread
// ---------------------------------------------------------------------------
__global__ void cast3_f32_f16(const float* __restrict__ s0, f16* __restrict__ d0, int n0,
                              const float* __restrict__ s1, f16* __restrict__ d1, int n1,
                              const float* __restrict__ s2, f16* __restrict__ d2, int n2) {
    int i = blockIdx.x * blockDim.x + threadIdx.x;
    const float* s; f16* d; int j;
    if (i < n0)                { s = s0; d = d0; j = i; }
    else if (i < n0 + n1)      { s = s1; d = d1; j = i - n0; }
    else if (i < n0 + n1 + n2) { s = s2; d = d2; j = i - n0 - n1; }
    else return;
    float4 v = ((const float4*)s)[j];
    f16x4 o = { (f16)v.x, (f16)v.y, (f16)v.z, (f16)v.w };
    ((f16x4*)d)[j] = o;
}

__device__ __forceinline__ void store4(f16* p, const f32x4& v) {
    f16x4 o = { (f16)v[0], (f16)v[1], (f16)v[2], (f16)v[3] };
    *(f16x4*)p = o;
}
__device__ __forceinline__ void store4(float* p, const f32x4& v) {
    float4 o = { v[0], v[1], v[2], v[3] };
    *(float4*)p = o;
}

// ---------------------------------------------------------------------------
// Barrier-free streaming MFMA GEMM: out[M,N] = A[M,K]@W[N,K]^T + bias.
// NO LDS: every MFMA fragment is a contiguous 16B row-segment of A/W, loaded
// straight global->VGPR (per-lane addr = row(lr)*K + lq*8 elems). Depth-2
// register ping-pong: tile k+1's (MT+NT) dwordx4 loads are in flight during
// tile k's MT*NT MFMAs; no __syncthreads anywhere -> no vmcnt(0) drains.
// 4 waves as 2x2; tile = (2*MT*16) x (2*NT*16).
// Operand-swapped mfma: lane&15 = out row, (lane>>4)*4+reg = out col
// -> 4-wide vector epilogue stores.
// ---------------------------------------------------------------------------
template <int MT, int NT, typename OT>
__global__ __launch_bounds__(256) void gemm_f16_stream(
    const f16* __restrict__ A,      // [M,K]
    const f16* __restrict__ W,      // [N,K]
    const float* __restrict__ bias, // [N]
    OT* __restrict__ out,           // [M,N]
    int M, int N, int K)
{
    const int tid  = threadIdx.x;
    const int lane = tid & 63;
    const int w    = tid >> 6;
    const int wr   = w >> 1;
    const int wc   = w & 1;
    const int lr   = lane & 15;
    const int lq   = lane >> 4;
    const int bm   = blockIdx.y * (2 * MT * 16);
    const int bn   = blockIdx.x * (2 * NT * 16);

    const f16* pa[MT];
    const f16* pb[NT];
#pragma unroll
    for (int mt = 0; mt < MT; ++mt)
        pa[mt] = A + (size_t)(bm + wr * MT * 16 + mt * 16 + lr) * K + lq * 8;
#pragma unroll
    for (int nt = 0; nt < NT; ++nt)
        pb[nt] = W + (size_t)(bn + wc * NT * 16 + nt * 16 + lr) * K + lq * 8;

    f32x4 acc[MT][NT] = {};
    f16x8 a0[MT], b0[NT], a1[MT], b1[NT];

    // prologue: load tile 0
#pragma unroll
    for (int mt = 0; mt < MT; ++mt) a0[mt] = *(const f16x8*)(pa[mt]);
#pragma unroll
    for (int nt = 0; nt < NT; ++nt) b0[nt] = *(const f16x8*)(pb[nt]);

    const int nk = K >> 5;
    for (int k = 0; k < nk; k += 2) {
        // prefetch k+1 while computing k
        if (k + 1 < nk) {
            int ko = (k + 1) << 5;
#pragma unroll
            for (int mt = 0; mt < MT; ++mt) a1[mt] = *(const f16x8*)(pa[mt] + ko);
#pragma unroll
            for (int nt = 0; nt < NT; ++nt) b1[nt] = *(const f16x8*)(pb[nt] + ko);
        }
#pragma unroll
        for (int mt = 0; mt < MT; ++mt)
#pragma unroll
            for (int nt = 0; nt < NT; ++nt)
                acc[mt][nt] = __builtin_amdgcn_mfma_f32_16x16x32_f16(
                    b0[nt], a0[mt], acc[mt][nt], 0, 0, 0);
        // prefetch k+2 while computing k+1
        if (k + 2 < nk) {
            int ko = (k + 2) << 5;
#pragma unroll
            for (int mt = 0; mt < MT; ++mt) a0[mt] = *(const f16x8*)(pa[mt] + ko);
#pragma unroll
            for (int nt = 0; nt < NT; ++nt) b0[nt] = *(const f16x8*)(pb[nt] + ko);
        }
        if (k + 1 < nk) {
#pragma unroll
            for (int mt = 0; mt < MT; ++mt)
#pragma unroll
                for (int nt = 0; nt < NT; ++nt)
                    acc[mt][nt] = __builtin_amdgcn_mfma_f32_16x16x32_f16(
                        b1[nt], a1[mt], acc[mt][nt], 0, 0, 0);
        }
    }

    // epilogue: lane holds out[row][col..col+3]
#pragma unroll
    for (int mt = 0; mt < MT; ++mt) {
        int row = bm + wr * MT * 16 + mt * 16 + lr;
#pragma unroll
        for (int nt = 0; nt < NT; ++nt) {
            int col = bn + wc * NT * 16 + nt * 16 + lq * 4;
            float4 bv = *(const float4*)(bias + col);
            f32x4 ov = acc[mt][nt];
            ov[0] += bv.x; ov[1] += bv.y; ov[2] += bv.z; ov[3] += bv.w;
            store4(out + (size_t)row * N + col, ov);
        }
    }
}

// ---------------------------------------------------------------------------
// MFMA local attention, window=128, hd=64 (operand-swapped, unchanged R5/R6).
// ---------------------------------------------------------------------------
#define WINDOW_SZ 128

__global__ __launch_bounds__(256) void local_attn_mfma(
    const f16* __restrict__ qkv,  // [N, 2304] f16: [q(12*64)|k|v]
    f16* __restrict__ out,        // [N, 768] f16
    int N)
{
    const int C  = 768;
    const int C3 = 2304;
    __shared__ f16 Ks[8 * 512];   // K A-frag segs (nt, ks)
    __shared__ f16 Vt[4096];      // swizzled V^T
    __shared__ f16 Ps[8 * 512];   // P B-frag segs (w, cs)

    const int tid  = threadIdx.x;
    const int lane = tid & 63;
    const int w    = tid >> 6;
    const int r15  = lane & 15;
    const int q4   = lane >> 4;
    const int ntiles = N >> 6;
    const int h  = blockIdx.x / ntiles;
    const int i0 = (blockIdx.x % ntiles) << 6;
    const int qoff = h * 64;
    const int koff = 768 + h * 64;
    const int voff = 1536 + h * 64;

    // Q B-frags (loop-invariant), prescaled by 0.125*log2(e)
    f16x8 qf[2];
    {
        const f16* qrow = qkv + (size_t)(i0 + w * 16 + r15) * C3 + qoff + q4 * 8;
        qf[0] = *(const f16x8*)(qrow);
        qf[1] = *(const f16x8*)(qrow + 32);
        const f16 qs = (f16)0.18033688f;
#pragma unroll
        for (int j = 0; j < 8; ++j) { qf[0][j] *= qs; qf[1][j] *= qs; }
    }

    const int vc0 = tid >> 3;
    const int vd0 = (tid & 7) * 8;
    const int va  = vd0 >> 3;

    f32x4 o[4] = {};
    float m_l = -1.0e30f, l_l = 0.f;

    for (int ch = 0; ch < 5; ++ch) {
        int jbase = i0 - 128 + ch * 64;
        if (jbase < 0 || jbase >= N) continue;
        bool need_mask = (ch == 0) || (ch == 4);

        __syncthreads();   // prior chunk's Ks/Vt reads done
        {
            const f16* kr = qkv + (size_t)(jbase + w * 16 + r15) * C3 + koff + q4 * 8;
            async_copy16(kr,      &Ks[(w * 2 + 0) * 512]);
            async_copy16(kr + 32, &Ks[(w * 2 + 1) * 512]);
        }
#pragma unroll
        for (int rep = 0; rep < 2; ++rep) {
            int c = vc0 + rep * 32;
            f16x8 v = *(const f16x8*)(qkv + (size_t)(jbase + c) * C3 + voff + vd0);
            int cc = c >> 3, c7 = c & 7;
#pragma unroll
            for (int j = 0; j < 8; ++j) {
                int x = (cc ^ va ^ j) & 7;
                Vt[(vd0 + j) * 64 + x * 8 + c7] = v[j];
            }
        }
        __syncthreads();

        // S^T = K @ Q^T : s[nt][r] = score(q=r15, key=nt*16+q4*4+r)
        f32x4 s[4] = {};
#pragma unroll
        for (int ks = 0; ks < 2; ++ks)
#pragma unroll
            for (int nt = 0; nt < 4; ++nt) {
                f16x8 kf = *(const f16x8*)&Ks[(nt * 2 + ks) * 512 + lane * 8];
                s[nt] = __builtin_amdgcn_mfma_f32_16x16x32_f16(kf, qf[ks], s[nt], 0, 0, 0);
            }

        if (need_mask) {
            int qg = i0 + w * 16 + r15;
#pragma unroll
            for (int nt = 0; nt < 4; ++nt)
#pragma unroll
                for (int r = 0; r < 4; ++r) {
                    int dist = qg - (jbase + nt * 16 + q4 * 4 + r);
                    if (dist < 0) dist = -dist;
                    if (dist > WINDOW_SZ) s[nt][r] = -3.0e38f;
                }
        }

        // online softmax (exp2 domain), row = this lane's q-row
        float rmax = -3.0e38f;
#pragma unroll
        for (int nt = 0; nt < 4; ++nt)
#pragma unroll
            for (int r = 0; r < 4; ++r) rmax = fmaxf(rmax, s[nt][r]);
        rmax = fmaxf(rmax, __shfl_xor(rmax, 16));
        rmax = fmaxf(rmax, __shfl_xor(rmax, 32));
        float mn = fmaxf(m_l, rmax);
        float al = EXP2F(m_l - mn);
        m_l = mn;
        float rs = 0.f;
#pragma unroll
        for (int nt = 0; nt < 4; ++nt)
#pragma unroll
            for (int r = 0; r < 4; ++r) {
                float p = EXP2F(s[nt][r] - mn);
                s[nt][r] = p;
                rs += p;
            }
        rs += __shfl_xor(rs, 16);
        rs += __shfl_xor(rs, 32);
        l_l = l_l * al + rs;
#pragma unroll
        for (int nd = 0; nd < 4; ++nd)
#pragma unroll
            for (int r = 0; r < 4; ++r) o[nd][r] *= al;

        // P -> Ps in B-frag layout (swizzled); per-wave buffer, no barrier
#pragma unroll
        for (int nt = 0; nt < 4; ++nt)
#pragma unroll
            for (int r = 0; r < 4; ++r) {
                int c  = nt * 16 + q4 * 4 + r;     // key index 0..63
                int cs = c >> 5;
                int c5 = c & 31;
                int ls = (c5 >> 3) * 16 + r15;
                int lss = ls ^ ((ls >> 3) & 7);
                Ps[(w * 2 + cs) * 512 + lss * 8 + (c5 & 7)] = (f16)s[nt][r];
            }

        // O^T += V^T @ P^T
        int lssr = lane ^ ((lane >> 3) & 7);
#pragma unroll
        for (int cs = 0; cs < 2; ++cs) {
            f16x8 pf = *(const f16x8*)&Ps[(w * 2 + cs) * 512 + lssr * 8];
#pragma unroll
            for (int nd = 0; nd < 4; ++nd) {
                int d = nd * 16 + r15;
                int x = ((cs * 4 + q4) ^ (d >> 3) ^ d) & 7;
                f16x8 vf = *(const f16x8*)&Vt[d * 64 + x * 8];
                o[nd] = __builtin_amdgcn_mfma_f32_16x16x32_f16(vf, pf, o[nd], 0, 0, 0);
            }
        }
    }

    // epilogue: lane holds q-row r15, d = nd*16 + q4*4 + (0..3) -> f16x4 stores
    float inv = 1.0f / l_l;
    int row = i0 + w * 16 + r15;
#pragma unroll
    for (int nd = 0; nd < 4; ++nd) {
        f16x4 ov = { (f16)(o[nd][0] * inv), (f16)(o[nd][1] * inv),
                     (f16)(o[nd][2] * inv), (f16)(o[nd][3] * inv) };
        *(f16x4*)(out + (size_t)row * C + qoff + nd * 16 + q4 * 4) = ov;
    }
}

// ---------------------------------------------------------------------------
extern "C" void kernel_launch(void* const* d_in, const int* in_sizes, int n_in,
                              void* d_out, int out_size, void* d_ws, size_t ws_size,
                              hipStream_t stream) {
    (void)n_in; (void)out_size; (void)ws_size;
    const float* x      = (const float*)d_in[0];
    const float* qkv_w  = (const float*)d_in[1];
    const float* qkv_b  = (const float*)d_in[2];
    const float* proj_w = (const float*)d_in[3];
    const float* proj_b = (const float*)d_in[4];
    float* outp = (float*)d_out;

    const int C    = in_sizes[2] / 3;     // 768
    const int Nseq = in_sizes[0] / C;     // 4096
    const int C3   = 3 * C;               // 2304

    char* ws = (char*)d_ws;
    f16* qkv_h = (f16*)ws;   ws += (size_t)Nseq * C3 * 2;   // 18.9 MB
    f16* xh    = (f16*)ws;   ws += (size_t)Nseq * C * 2;    // 6.3 MB (reused as attn_h)
    f16* wh_q  = (f16*)ws;   ws += (size_t)C3 * C * 2;      // 3.5 MB
    f16* wh_p  = (f16*)ws;                                   // 1.2 MB
    f16* attn_h = xh;   // alias: xh dead after GEMM1

    dim3 blk(256);
    {
        int n0 = Nseq * C / 4, n1 = C3 * C / 4, n2 = C * C / 4;
        int tot = n0 + n1 + n2;
        cast3_f32_f16<<<dim3((tot + 255) / 256), blk, 0, stream>>>(
            x, xh, n0, qkv_w, wh_q, n1, proj_w, wh_p, n2);
    }
    // qkv (f16) = x @ qkv_w^T + qkv_b   (128x128 tiles, 576 blocks, no barriers)
    gemm_f16_stream<4, 4, f16><<<dim3(C3 / 128, Nseq / 128), blk, 0, stream>>>(
        xh, wh_q, qkv_b, qkv_h, Nseq, C3, C);
    // banded attention -> f16
    local_attn_mfma<<<dim3((C / 64) * (Nseq / 64)), blk, 0, stream>>>(
        qkv_h, attn_h, Nseq);
    // out (f32) = attn @ proj_w^T + proj_b   (64x64 tiles, 768 blocks)
    gemm_f16_stream<2, 2, float><<<dim3(C / 64, Nseq / 64), blk, 0, stream>>>(
        attn_h, wh_p, proj_b, outp, Nseq, C, C);
}

// Round 8
// 159.797 us; speedup vs baseline: 1.2403x; 1.2403x over previous
//
#include <hip/hip_runtime.h>
#include <hip/hip_fp16.h>
#include <cmath>

typedef _Float16 f16;
typedef __attribute__((ext_vector_type(8))) _Float16 f16x8;
typedef __attribute__((ext_vector_type(4))) _Float16 f16x4;
typedef __attribute__((ext_vector_type(4))) float f32x4;

#define EXP2F(x) __builtin_amdgcn_exp2f(x)

// ---------------------------------------------------------------------------
// fused f32 -> f16 cast over 3 segments (x, qkv_w, proj_w), 4 elems/thread
// ---------------------------------------------------------------------------
__global__ void cast3_f32_f16(const float* __restrict__ s0, f16* __restrict__ d0, int n0,
                              const float* __restrict__ s1, f16* __restrict__ d1, int n1,
                              const float* __restrict__ s2, f16* __restrict__ d2, int n2) {
    int i = blockIdx.x * blockDim.x + threadIdx.x;
    const float* s; f16* d; int j;
    if (i < n0)                { s = s0; d = d0; j = i; }
    else if (i < n0 + n1)      { s = s1; d = d1; j = i - n0; }
    else if (i < n0 + n1 + n2) { s = s2; d = d2; j = i - n0 - n1; }
    else return;
    float4 v = ((const float4*)s)[j];
    f16x4 o = { (f16)v.x, (f16)v.y, (f16)v.z, (f16)v.w };
    ((f16x4*)d)[j] = o;
}

__device__ __forceinline__ void store4(f16* p, const f32x4& v) {
    f16x4 o = { (f16)v[0], (f16)v[1], (f16)v[2], (f16)v[3] };
    *(f16x4*)p = o;
}
__device__ __forceinline__ void store4(float* p, const f32x4& v) {
    float4 o = { v[0], v[1], v[2], v[3] };
    *(float4*)p = o;
}

// ---------------------------------------------------------------------------
// Register-staged pipelined MFMA GEMM: out = A[M,K] @ W[N,K]^T + bias.
// Tile (WR*MT*16) x (WC*NT*16), BK=32, 4 waves (WR x WC grid).
// Double-buffered frag-ready LDS. Pipeline per iter k:
//   1. global->VGPR loads of tile k+1 (issued, not waited)
//   2. ds_read frags of tile k from buf[k&1]  (lgkm wait)
//   3. MT*NT MFMAs                            (covers the global loads)
//   4. ds_write staged regs -> buf[k&1 ^ 1]   (vmcnt wait lands HERE)
//   5. __syncthreads                          (vmcnt already 0 -> cheap)
// Buffer written at k is the one read at k-1 (barrier-protected).
// Operand-swapped mfma: lane&15 = out row, (lane>>4)*4+reg = out col.
// ---------------------------------------------------------------------------
template <int WR, int WC, int MT, int NT, typename OT>
__global__ __launch_bounds__(256) void gemm_f16_pipe(
    const f16* __restrict__ A,      // [M,K]
    const f16* __restrict__ W,      // [N,K]
    const float* __restrict__ bias, // [N]
    OT* __restrict__ out,           // [M,N]
    int M, int N, int K)
{
    constexpr int ACH = WR * MT;     // 16-row chunks of A tile
    constexpr int BCH = WC * NT;
    constexpr int AR  = ACH / 4;     // chunks staged per wave
    constexpr int BR  = BCH / 4;
    __shared__ f16 Ash[2][ACH * 512];
    __shared__ f16 Bsh[2][BCH * 512];

    const int tid  = threadIdx.x;
    const int lane = tid & 63;
    const int w    = tid >> 6;
    const int wr   = w / WC;
    const int wc   = w % WC;
    const int lr   = lane & 15;
    const int lq   = lane >> 4;
    const int bm   = blockIdx.y * (WR * MT * 16);
    const int bn   = blockIdx.x * (WC * NT * 16);

    const f16* ga[AR];
    const f16* gb[BR];
#pragma unroll
    for (int r = 0; r < AR; ++r)
        ga[r] = A + (size_t)(bm + (w * AR + r) * 16 + lr) * K + lq * 8;
#pragma unroll
    for (int r = 0; r < BR; ++r)
        gb[r] = W + (size_t)(bn + (w * BR + r) * 16 + lr) * K + lq * 8;

    f32x4 acc[MT][NT] = {};
    f16x8 sa[AR], sb[BR];

    // prologue: tile 0 -> regs -> LDS buf0
#pragma unroll
    for (int r = 0; r < AR; ++r) sa[r] = *(const f16x8*)(ga[r]);
#pragma unroll
    for (int r = 0; r < BR; ++r) sb[r] = *(const f16x8*)(gb[r]);
#pragma unroll
    for (int r = 0; r < AR; ++r) *(f16x8*)&Ash[0][(w * AR + r) * 512 + lane * 8] = sa[r];
#pragma unroll
    for (int r = 0; r < BR; ++r) *(f16x8*)&Bsh[0][(w * BR + r) * 512 + lane * 8] = sb[r];
    __syncthreads();

    const int nk = K >> 5;
    for (int k = 0; k < nk; ++k) {
        const int cur = k & 1;
        if (k + 1 < nk) {
            const int ko = (k + 1) << 5;
#pragma unroll
            for (int r = 0; r < AR; ++r) sa[r] = *(const f16x8*)(ga[r] + ko);
#pragma unroll
            for (int r = 0; r < BR; ++r) sb[r] = *(const f16x8*)(gb[r] + ko);
        }
        f16x8 af[MT], bf[NT];
#pragma unroll
        for (int mt = 0; mt < MT; ++mt)
            af[mt] = *(const f16x8*)&Ash[cur][(wr * MT + mt) * 512 + lane * 8];
#pragma unroll
        for (int nt = 0; nt < NT; ++nt)
            bf[nt] = *(const f16x8*)&Bsh[cur][(wc * NT + nt) * 512 + lane * 8];
#pragma unroll
        for (int mt = 0; mt < MT; ++mt)
#pragma unroll
            for (int nt = 0; nt < NT; ++nt)
                acc[mt][nt] = __builtin_amdgcn_mfma_f32_16x16x32_f16(
                    bf[nt], af[mt], acc[mt][nt], 0, 0, 0);
        if (k + 1 < nk) {
#pragma unroll
            for (int r = 0; r < AR; ++r)
                *(f16x8*)&Ash[cur ^ 1][(w * AR + r) * 512 + lane * 8] = sa[r];
#pragma unroll
            for (int r = 0; r < BR; ++r)
                *(f16x8*)&Bsh[cur ^ 1][(w * BR + r) * 512 + lane * 8] = sb[r];
        }
        __syncthreads();
    }

    // epilogue: lane holds out[row][col..col+3]
#pragma unroll
    for (int mt = 0; mt < MT; ++mt) {
        int row = bm + (wr * MT + mt) * 16 + lr;
#pragma unroll
        for (int nt = 0; nt < NT; ++nt) {
            int col = bn + (wc * NT + nt) * 16 + lq * 4;
            float4 bv = *(const float4*)(bias + col);
            f32x4 ov = acc[mt][nt];
            ov[0] += bv.x; ov[1] += bv.y; ov[2] += bv.z; ov[3] += bv.w;
            store4(out + (size_t)row * N + col, ov);
        }
    }
}

// ---------------------------------------------------------------------------
// MFMA local attention, window=128, hd=64, register-staged double buffer.
// Per chunk ch: prefetch K/V of ch+1 into regs, compute S/softmax/PV from
// buf[p], ds_write staged regs into buf[p^1] (vmcnt wait after compute),
// ONE barrier per chunk. LDS = 2*8 + 2*8 + 8 = 40 KB -> 4 blocks/CU.
// ---------------------------------------------------------------------------
#define WINDOW_SZ 128

__global__ __launch_bounds__(256) void local_attn_mfma(
    const f16* __restrict__ qkv,  // [N, 2304] f16: [q(12*64)|k|v]
    f16* __restrict__ out,        // [N, 768] f16
    int N)
{
    const int C  = 768;
    const int C3 = 2304;
    __shared__ f16 Ks[2][4096];   // K A-frag segs (nt, ks)
    __shared__ f16 Vt[2][4096];   // swizzled V^T
    __shared__ f16 Ps[4096];      // P B-frag segs (w, cs)

    const int tid  = threadIdx.x;
    const int lane = tid & 63;
    const int w    = tid >> 6;
    const int r15  = lane & 15;
    const int q4   = lane >> 4;
    const int ntiles = N >> 6;
    const int h  = blockIdx.x / ntiles;
    const int i0 = (blockIdx.x % ntiles) << 6;
    const int qoff = h * 64;
    const int koff = 768 + h * 64;
    const int voff = 1536 + h * 64;

    // Q B-frags (loop-invariant), prescaled by 0.125*log2(e)
    f16x8 qf[2];
    {
        const f16* qrow = qkv + (size_t)(i0 + w * 16 + r15) * C3 + qoff + q4 * 8;
        qf[0] = *(const f16x8*)(qrow);
        qf[1] = *(const f16x8*)(qrow + 32);
        const f16 qs = (f16)0.18033688f;
#pragma unroll
        for (int j = 0; j < 8; ++j) { qf[0][j] *= qs; qf[1][j] *= qs; }
    }

    const int vc0 = tid >> 3;
    const int vd0 = (tid & 7) * 8;
    const int va  = vd0 >> 3;

    f32x4 o[4] = {};
    float m_l = -1.0e30f, l_l = 0.f;

    const int lo = (i0 >= 128) ? 0 : ((128 - i0) >> 6);
    int hi = (N + 64 - i0) >> 6; if (hi > 4) hi = 4;

    f16x8 k0, k1, v0, v1;
    // prologue: load chunk lo -> regs -> LDS buf0
    {
        int jbase = i0 - 128 + lo * 64;
        const f16* kr = qkv + (size_t)(jbase + w * 16 + r15) * C3 + koff + q4 * 8;
        k0 = *(const f16x8*)(kr);
        k1 = *(const f16x8*)(kr + 32);
        v0 = *(const f16x8*)(qkv + (size_t)(jbase + vc0) * C3 + voff + vd0);
        v1 = *(const f16x8*)(qkv + (size_t)(jbase + vc0 + 32) * C3 + voff + vd0);
        *(f16x8*)&Ks[0][(w * 2 + 0) * 512 + lane * 8] = k0;
        *(f16x8*)&Ks[0][(w * 2 + 1) * 512 + lane * 8] = k1;
        int cc0 = vc0 >> 3, c7 = vc0 & 7;
#pragma unroll
        for (int j = 0; j < 8; ++j) {
            Vt[0][(vd0 + j) * 64 + ((cc0 ^ va ^ j) & 7) * 8 + c7] = v0[j];
            Vt[0][(vd0 + j) * 64 + (((cc0 + 4) ^ va ^ j) & 7) * 8 + c7] = v1[j];
        }
    }
    __syncthreads();

    for (int ch = lo; ch <= hi; ++ch) {
        const int p = (ch - lo) & 1;
        const int jbase = i0 - 128 + ch * 64;
        const bool need_mask = (ch == 0) || (ch == 4);

        // prefetch chunk ch+1 into regs (no wait)
        if (ch < hi) {
            int jn = jbase + 64;
            const f16* kr = qkv + (size_t)(jn + w * 16 + r15) * C3 + koff + q4 * 8;
            k0 = *(const f16x8*)(kr);
            k1 = *(const f16x8*)(kr + 32);
            v0 = *(const f16x8*)(qkv + (size_t)(jn + vc0) * C3 + voff + vd0);
            v1 = *(const f16x8*)(qkv + (size_t)(jn + vc0 + 32) * C3 + voff + vd0);
        }

        // S^T = K @ Q^T : s[nt][r] = score(q=r15, key=nt*16+q4*4+r)
        f32x4 s[4] = {};
#pragma unroll
        for (int ks = 0; ks < 2; ++ks)
#pragma unroll
            for (int nt = 0; nt < 4; ++nt) {
                f16x8 kf = *(const f16x8*)&Ks[p][(nt * 2 + ks) * 512 + lane * 8];
                s[nt] = __builtin_amdgcn_mfma_f32_16x16x32_f16(kf, qf[ks], s[nt], 0, 0, 0);
            }

        if (need_mask) {
            int qg = i0 + w * 16 + r15;
#pragma unroll
            for (int nt = 0; nt < 4; ++nt)
#pragma unroll
                for (int r = 0; r < 4; ++r) {
                    int dist = qg - (jbase + nt * 16 + q4 * 4 + r);
                    if (dist < 0) dist = -dist;
                    if (dist > WINDOW_SZ) s[nt][r] = -3.0e38f;
                }
        }

        // online softmax (exp2 domain), row = this lane's q-row
        float rmax = -3.0e38f;
#pragma unroll
        for (int nt = 0; nt < 4; ++nt)
#pragma unroll
            for (int r = 0; r < 4; ++r) rmax = fmaxf(rmax, s[nt][r]);
        rmax = fmaxf(rmax, __shfl_xor(rmax, 16));
        rmax = fmaxf(rmax, __shfl_xor(rmax, 32));
        float mn = fmaxf(m_l, rmax);
        float al = EXP2F(m_l - mn);
        m_l = mn;
        float rs = 0.f;
#pragma unroll
        for (int nt = 0; nt < 4; ++nt)
#pragma unroll
            for (int r = 0; r < 4; ++r) {
                float pv = EXP2F(s[nt][r] - mn);
                s[nt][r] = pv;
                rs += pv;
            }
        rs += __shfl_xor(rs, 16);
        rs += __shfl_xor(rs, 32);
        l_l = l_l * al + rs;
#pragma unroll
        for (int nd = 0; nd < 4; ++nd)
#pragma unroll
            for (int r = 0; r < 4; ++r) o[nd][r] *= al;

        // P -> Ps in B-frag layout (swizzled); per-wave buffer, no barrier
#pragma unroll
        for (int nt = 0; nt < 4; ++nt)
#pragma unroll
            for (int r = 0; r < 4; ++r) {
                int c  = nt * 16 + q4 * 4 + r;
                int cs = c >> 5;
                int c5 = c & 31;
                int ls = (c5 >> 3) * 16 + r15;
                int lss = ls ^ ((ls >> 3) & 7);
                Ps[(w * 2 + cs) * 512 + lss * 8 + (c5 & 7)] = (f16)s[nt][r];
            }

        // O^T += V^T @ P^T
        int lssr = lane ^ ((lane >> 3) & 7);
#pragma unroll
        for (int cs = 0; cs < 2; ++cs) {
            f16x8 pf = *(const f16x8*)&Ps[(w * 2 + cs) * 512 + lssr * 8];
#pragma unroll
            for (int nd = 0; nd < 4; ++nd) {
                int d = nd * 16 + r15;
                int x = ((cs * 4 + q4) ^ (d >> 3) ^ d) & 7;
                f16x8 vf = *(const f16x8*)&Vt[p][d * 64 + x * 8];
                o[nd] = __builtin_amdgcn_mfma_f32_16x16x32_f16(vf, pf, o[nd], 0, 0, 0);
            }
        }

        // stage chunk ch+1 into buf p^1 (vmcnt wait lands here, after compute)
        if (ch < hi) {
            *(f16x8*)&Ks[p ^ 1][(w * 2 + 0) * 512 + lane * 8] = k0;
            *(f16x8*)&Ks[p ^ 1][(w * 2 + 1) * 512 + lane * 8] = k1;
            int cc0 = vc0 >> 3, c7 = vc0 & 7;
#pragma unroll
            for (int j = 0; j < 8; ++j) {
                Vt[p ^ 1][(vd0 + j) * 64 + ((cc0 ^ va ^ j) & 7) * 8 + c7] = v0[j];
                Vt[p ^ 1][(vd0 + j) * 64 + (((cc0 + 4) ^ va ^ j) & 7) * 8 + c7] = v1[j];
            }
        }
        __syncthreads();
    }

    // epilogue: lane holds q-row r15, d = nd*16 + q4*4 + (0..3) -> f16x4 stores
    float inv = 1.0f / l_l;
    int row = i0 + w * 16 + r15;
#pragma unroll
    for (int nd = 0; nd < 4; ++nd) {
        f16x4 ov = { (f16)(o[nd][0] * inv), (f16)(o[nd][1] * inv),
                     (f16)(o[nd][2] * inv), (f16)(o[nd][3] * inv) };
        *(f16x4*)(out + (size_t)row * C + qoff + nd * 16 + q4 * 4) = ov;
    }
}

// ---------------------------------------------------------------------------
extern "C" void kernel_launch(void* const* d_in, const int* in_sizes, int n_in,
                              void* d_out, int out_size, void* d_ws, size_t ws_size,
                              hipStream_t stream) {
    (void)n_in; (void)out_size; (void)ws_size;
    const float* x      = (const float*)d_in[0];
    const float* qkv_w  = (const float*)d_in[1];
    const float* qkv_b  = (const float*)d_in[2];
    const float* proj_w = (const float*)d_in[3];
    const float* proj_b = (const float*)d_in[4];
    float* outp = (float*)d_out;

    const int C    = in_sizes[2] / 3;     // 768
    const int Nseq = in_sizes[0] / C;     // 4096
    const int C3   = 3 * C;               // 2304

    char* ws = (char*)d_ws;
    f16* qkv_h = (f16*)ws;   ws += (size_t)Nseq * C3 * 2;   // 18.9 MB
    f16* xh    = (f16*)ws;   ws += (size_t)Nseq * C * 2;    // 6.3 MB (reused as attn_h)
    f16* wh_q  = (f16*)ws;   ws += (size_t)C3 * C * 2;      // 3.5 MB
    f16* wh_p  = (f16*)ws;                                   // 1.2 MB
    f16* attn_h = xh;   // alias: xh dead after GEMM1

    dim3 blk(256);
    {
        int n0 = Nseq * C / 4, n1 = C3 * C / 4, n2 = C * C / 4;
        int tot = n0 + n1 + n2;
        cast3_f32_f16<<<dim3((tot + 255) / 256), blk, 0, stream>>>(
            x, xh, n0, qkv_w, wh_q, n1, proj_w, wh_p, n2);
    }
    // qkv (f16) = x @ qkv_w^T + qkv_b   (128x128 tiles, 576 blocks)
    gemm_f16_pipe<2, 2, 4, 4, f16><<<dim3(C3 / 128, Nseq / 128), blk, 0, stream>>>(
        xh, wh_q, qkv_b, qkv_h, Nseq, C3, C);
    // banded attention -> f16
    local_attn_mfma<<<dim3((C / 64) * (Nseq / 64)), blk, 0, stream>>>(
        qkv_h, attn_h, Nseq);
    // out (f32) = attn @ proj_w^T + proj_b   (64x64 tiles, 768 blocks)
    gemm_f16_pipe<2, 2, 2, 2, float><<<dim3(C / 64, Nseq / 64), blk, 0, stream>>>(
        attn_h, wh_p, proj_b, outp, Nseq, C, C);
}

// Round 9
// 133.335 us; speedup vs baseline: 1.4864x; 1.1985x over previous
//
#include <hip/hip_runtime.h>
#include <hip/hip_fp16.h>
#include <cmath>

typedef _Float16 f16;
typedef __attribute__((ext_vector_type(8))) _Float16 f16x8;
typedef __attribute__((ext_vector_type(4))) _Float16 f16x4;
typedef __attribute__((ext_vector_type(4))) float f32x4;

#define EXP2F(x) __builtin_amdgcn_exp2f(x)

// ---------------------------------------------------------------------------
// Packed operand layout ("frag-linear"): matrix [R,K] (R%16==0, K%32==0) is
// stored as chunks of 16 rows x 32 k = 512 f16 = 1 KB. Chunk id
// cid = (r>>4)*(K>>5) + (k>>5). Within a chunk, lane l = (r&15) + ((k>>3)&3)*16
// holds the 8 f16 at elem offset lane*8 — exactly the mfma 16x16x32 A/B
// operand fragment. Staging a chunk = ONE fully-contiguous 1 KB wave-load.
// ---------------------------------------------------------------------------

// pack 3 f32 matrices -> f16 packed chunks; one wave per chunk.
// Reads: 16 rows x 128 B contiguous (cache-line perfect). Writes: 1 KB linear.
__global__ void pack3_f32_f16(
    const float* __restrict__ s0, f16* __restrict__ d0, int nc0, int kc0,
    const float* __restrict__ s1, f16* __restrict__ d1, int nc1, int kc1,
    const float* __restrict__ s2, f16* __restrict__ d2, int nc2, int kc2)
{
    int wid  = (blockIdx.x * blockDim.x + threadIdx.x) >> 6;
    int lane = threadIdx.x & 63;
    const float* s; f16* d; int cid, KC;
    if (wid < nc0)                  { s = s0; d = d0; cid = wid;             KC = kc0; }
    else if (wid < nc0 + nc1)       { s = s1; d = d1; cid = wid - nc0;       KC = kc1; }
    else if (wid < nc0 + nc1 + nc2) { s = s2; d = d2; cid = wid - nc0 - nc1; KC = kc2; }
    else return;
    int rc = cid / KC, kc = cid % KC;
    int K  = KC << 5;
    const float* src = s + (size_t)(rc * 16 + (lane & 15)) * K + kc * 32 + (lane >> 4) * 8;
    float4 v0 = *(const float4*)src;
    float4 v1 = *(const float4*)(src + 4);
    f16x8 o = { (f16)v0.x, (f16)v0.y, (f16)v0.z, (f16)v0.w,
                (f16)v1.x, (f16)v1.y, (f16)v1.z, (f16)v1.w };
    *(f16x8*)(d + (size_t)cid * 512 + lane * 8) = o;
}

__device__ __forceinline__ void store4(f16* p, const f32x4& v) {
    f16x4 o = { (f16)v[0], (f16)v[1], (f16)v[2], (f16)v[3] };
    *(f16x4*)p = o;
}
__device__ __forceinline__ void store4(float* p, const f32x4& v) {
    float4 o = { v[0], v[1], v[2], v[3] };
    *(float4*)p = o;
}

// ---------------------------------------------------------------------------
// Packed-operand MFMA GEMM: out = A[M,K] @ W[N,K]^T + bias, both inputs in
// frag-linear chunks. Tile (WR*MT*16) x (WC*NT*16), BK=64 (KK=2 k-chunks),
// 4 waves. Register-staged double-buffered LDS (R8 pipeline): prefetch
// global->VGPR (contiguous 1 KB/instr!), ds_read frags, MFMA, ds_write
// staged regs (vmcnt wait lands post-MFMA), one barrier/iter.
// Operand-swapped mfma: lane&15 = out row, (lane>>4)*4+reg = out col.
// ---------------------------------------------------------------------------
template <int WR, int WC, int MT, int NT, typename OT>
__global__ __launch_bounds__(256) void gemm_f16_packed(
    const f16* __restrict__ Ap,     // packed [M/16 * K/32] chunks
    const f16* __restrict__ Wp,     // packed [N/16 * K/32] chunks
    const float* __restrict__ bias, // [N]
    OT* __restrict__ out,           // [M,N] row-major
    int M, int N, int K)
{
    constexpr int KK  = 2;              // k-chunks per iter (BK=64)
    constexpr int ACH = WR * MT * KK;
    constexpr int BCH = WC * NT * KK;
    constexpr int AR  = ACH / 4;
    constexpr int BR  = BCH / 4;
    __shared__ f16 Ash[2][ACH * 512];
    __shared__ f16 Bsh[2][BCH * 512];

    const int tid  = threadIdx.x;
    const int lane = tid & 63;
    const int w    = tid >> 6;
    const int wr   = w / WC;
    const int wc   = w % WC;
    const int lr   = lane & 15;
    const int lq   = lane >> 4;
    const int bm   = blockIdx.y * (WR * MT * 16);
    const int bn   = blockIdx.x * (WC * NT * 16);
    const int KC   = K >> 5;

    const f16* ga[AR];
    const f16* gb[BR];
#pragma unroll
    for (int r = 0; r < AR; ++r) {
        int s = w * AR + r, rl = s / KK, kk = s % KK;
        ga[r] = Ap + ((size_t)((bm >> 4) + rl) * KC + kk) * 512 + lane * 8;
    }
#pragma unroll
    for (int r = 0; r < BR; ++r) {
        int s = w * BR + r, rl = s / KK, kk = s % KK;
        gb[r] = Wp + ((size_t)((bn >> 4) + rl) * KC + kk) * 512 + lane * 8;
    }

    f32x4 acc[MT][NT] = {};
    f16x8 sa[AR], sb[BR];

    // prologue: tile 0 -> regs -> LDS buf0
#pragma unroll
    for (int r = 0; r < AR; ++r) sa[r] = *(const f16x8*)(ga[r]);
#pragma unroll
    for (int r = 0; r < BR; ++r) sb[r] = *(const f16x8*)(gb[r]);
#pragma unroll
    for (int r = 0; r < AR; ++r) *(f16x8*)&Ash[0][(w * AR + r) * 512 + lane * 8] = sa[r];
#pragma unroll
    for (int r = 0; r < BR; ++r) *(f16x8*)&Bsh[0][(w * BR + r) * 512 + lane * 8] = sb[r];
    __syncthreads();

    const int nk = K >> 6;
    for (int k = 0; k < nk; ++k) {
        const int cur = k & 1;
        if (k + 1 < nk) {
            const int ko = (k + 1) * KK * 512;
#pragma unroll
            for (int r = 0; r < AR; ++r) sa[r] = *(const f16x8*)(ga[r] + ko);
#pragma unroll
            for (int r = 0; r < BR; ++r) sb[r] = *(const f16x8*)(gb[r] + ko);
        }
        f16x8 af[MT][KK], bf[NT][KK];
#pragma unroll
        for (int mt = 0; mt < MT; ++mt)
#pragma unroll
            for (int kk = 0; kk < KK; ++kk)
                af[mt][kk] = *(const f16x8*)&Ash[cur][((wr * MT + mt) * KK + kk) * 512 + lane * 8];
#pragma unroll
        for (int nt = 0; nt < NT; ++nt)
#pragma unroll
            for (int kk = 0; kk < KK; ++kk)
                bf[nt][kk] = *(const f16x8*)&Bsh[cur][((wc * NT + nt) * KK + kk) * 512 + lane * 8];
#pragma unroll
        for (int kk = 0; kk < KK; ++kk)
#pragma unroll
            for (int mt = 0; mt < MT; ++mt)
#pragma unroll
                for (int nt = 0; nt < NT; ++nt)
                    acc[mt][nt] = __builtin_amdgcn_mfma_f32_16x16x32_f16(
                        bf[nt][kk], af[mt][kk], acc[mt][nt], 0, 0, 0);
        if (k + 1 < nk) {
#pragma unroll
            for (int r = 0; r < AR; ++r)
                *(f16x8*)&Ash[cur ^ 1][(w * AR + r) * 512 + lane * 8] = sa[r];
#pragma unroll
            for (int r = 0; r < BR; ++r)
                *(f16x8*)&Bsh[cur ^ 1][(w * BR + r) * 512 + lane * 8] = sb[r];
        }
        __syncthreads();
    }

    // epilogue: lane holds out[row][col..col+3]
#pragma unroll
    for (int mt = 0; mt < MT; ++mt) {
        int row = bm + (wr * MT + mt) * 16 + lr;
#pragma unroll
        for (int nt = 0; nt < NT; ++nt) {
            int col = bn + (wc * NT + nt) * 16 + lq * 4;
            float4 bv = *(const float4*)(bias + col);
            f32x4 ov = acc[mt][nt];
            ov[0] += bv.x; ov[1] += bv.y; ov[2] += bv.z; ov[3] += bv.w;
            store4(out + (size_t)row * N + col, ov);
        }
    }
}

// ---------------------------------------------------------------------------
// MFMA local attention (R8 structure), epilogue writes PACKED output chunks
// so GEMM2 gets frag-linear A. LDS = 2*8 + 2*8 + 8 = 40 KB.
// ---------------------------------------------------------------------------
#define WINDOW_SZ 128

__global__ __launch_bounds__(256) void local_attn_mfma(
    const f16* __restrict__ qkv,  // [N, 2304] f16 row-major: [q|k|v]
    f16* __restrict__ outp,       // packed [N/16 * C/32] chunks
    int N)
{
    const int C  = 768;
    const int C3 = 2304;
    __shared__ f16 Ks[2][4096];
    __shared__ f16 Vt[2][4096];
    __shared__ f16 Ps[4096];

    const int tid  = threadIdx.x;
    const int lane = tid & 63;
    const int w    = tid >> 6;
    const int r15  = lane & 15;
    const int q4   = lane >> 4;
    const int ntiles = N >> 6;
    const int h  = blockIdx.x / ntiles;
    const int i0 = (blockIdx.x % ntiles) << 6;
    const int qoff = h * 64;
    const int koff = 768 + h * 64;
    const int voff = 1536 + h * 64;

    f16x8 qf[2];
    {
        const f16* qrow = qkv + (size_t)(i0 + w * 16 + r15) * C3 + qoff + q4 * 8;
        qf[0] = *(const f16x8*)(qrow);
        qf[1] = *(const f16x8*)(qrow + 32);
        const f16 qs = (f16)0.18033688f;   // 0.125 * log2(e)
#pragma unroll
        for (int j = 0; j < 8; ++j) { qf[0][j] *= qs; qf[1][j] *= qs; }
    }

    const int vc0 = tid >> 3;
    const int vd0 = (tid & 7) * 8;
    const int va  = vd0 >> 3;

    f32x4 o[4] = {};
    float m_l = -1.0e30f, l_l = 0.f;

    const int lo = (i0 >= 128) ? 0 : ((128 - i0) >> 6);
    int hi = (N + 64 - i0) >> 6; if (hi > 4) hi = 4;

    f16x8 k0, k1, v0, v1;
    {
        int jbase = i0 - 128 + lo * 64;
        const f16* kr = qkv + (size_t)(jbase + w * 16 + r15) * C3 + koff + q4 * 8;
        k0 = *(const f16x8*)(kr);
        k1 = *(const f16x8*)(kr + 32);
        v0 = *(const f16x8*)(qkv + (size_t)(jbase + vc0) * C3 + voff + vd0);
        v1 = *(const f16x8*)(qkv + (size_t)(jbase + vc0 + 32) * C3 + voff + vd0);
        *(f16x8*)&Ks[0][(w * 2 + 0) * 512 + lane * 8] = k0;
        *(f16x8*)&Ks[0][(w * 2 + 1) * 512 + lane * 8] = k1;
        int cc0 = vc0 >> 3, c7 = vc0 & 7;
#pragma unroll
        for (int j = 0; j < 8; ++j) {
            Vt[0][(vd0 + j) * 64 + ((cc0 ^ va ^ j) & 7) * 8 + c7] = v0[j];
            Vt[0][(vd0 + j) * 64 + (((cc0 + 4) ^ va ^ j) & 7) * 8 + c7] = v1[j];
        }
    }
    __syncthreads();

    for (int ch = lo; ch <= hi; ++ch) {
        const int p = (ch - lo) & 1;
        const int jbase = i0 - 128 + ch * 64;
        const bool need_mask = (ch == 0) || (ch == 4);

        if (ch < hi) {
            int jn = jbase + 64;
            const f16* kr = qkv + (size_t)(jn + w * 16 + r15) * C3 + koff + q4 * 8;
            k0 = *(const f16x8*)(kr);
            k1 = *(const f16x8*)(kr + 32);
            v0 = *(const f16x8*)(qkv + (size_t)(jn + vc0) * C3 + voff + vd0);
            v1 = *(const f16x8*)(qkv + (size_t)(jn + vc0 + 32) * C3 + voff + vd0);
        }

        f32x4 s[4] = {};
#pragma unroll
        for (int ks = 0; ks < 2; ++ks)
#pragma unroll
            for (int nt = 0; nt < 4; ++nt) {
                f16x8 kf = *(const f16x8*)&Ks[p][(nt * 2 + ks) * 512 + lane * 8];
                s[nt] = __builtin_amdgcn_mfma_f32_16x16x32_f16(kf, qf[ks], s[nt], 0, 0, 0);
            }

        if (need_mask) {
            int qg = i0 + w * 16 + r15;
#pragma unroll
            for (int nt = 0; nt < 4; ++nt)
#pragma unroll
                for (int r = 0; r < 4; ++r) {
                    int dist = qg - (jbase + nt * 16 + q4 * 4 + r);
                    if (dist < 0) dist = -dist;
                    if (dist > WINDOW_SZ) s[nt][r] = -3.0e38f;
                }
        }

        float rmax = -3.0e38f;
#pragma unroll
        for (int nt = 0; nt < 4; ++nt)
#pragma unroll
            for (int r = 0; r < 4; ++r) rmax = fmaxf(rmax, s[nt][r]);
        rmax = fmaxf(rmax, __shfl_xor(rmax, 16));
        rmax = fmaxf(rmax, __shfl_xor(rmax, 32));
        float mn = fmaxf(m_l, rmax);
        float al = EXP2F(m_l - mn);
        m_l = mn;
        float rs = 0.f;
#pragma unroll
        for (int nt = 0; nt < 4; ++nt)
#pragma unroll
            for (int r = 0; r < 4; ++r) {
                float pv = EXP2F(s[nt][r] - mn);
                s[nt][r] = pv;
                rs += pv;
            }
        rs += __shfl_xor(rs, 16);
        rs += __shfl_xor(rs, 32);
        l_l = l_l * al + rs;
#pragma unroll
        for (int nd = 0; nd < 4; ++nd)
#pragma unroll
            for (int r = 0; r < 4; ++r) o[nd][r] *= al;

#pragma unroll
        for (int nt = 0; nt < 4; ++nt)
#pragma unroll
            for (int r = 0; r < 4; ++r) {
                int c  = nt * 16 + q4 * 4 + r;
                int cs = c >> 5;
                int c5 = c & 31;
                int ls = (c5 >> 3) * 16 + r15;
                int lss = ls ^ ((ls >> 3) & 7);
                Ps[(w * 2 + cs) * 512 + lss * 8 + (c5 & 7)] = (f16)s[nt][r];
            }

        int lssr = lane ^ ((lane >> 3) & 7);
#pragma unroll
        for (int cs = 0; cs < 2; ++cs) {
            f16x8 pf = *(const f16x8*)&Ps[(w * 2 + cs) * 512 + lssr * 8];
#pragma unroll
            for (int nd = 0; nd < 4; ++nd) {
                int d = nd * 16 + r15;
                int x = ((cs * 4 + q4) ^ (d >> 3) ^ d) & 7;
                f16x8 vf = *(const f16x8*)&Vt[p][d * 64 + x * 8];
                o[nd] = __builtin_amdgcn_mfma_f32_16x16x32_f16(vf, pf, o[nd], 0, 0, 0);
            }
        }

        if (ch < hi) {
            *(f16x8*)&Ks[p ^ 1][(w * 2 + 0) * 512 + lane * 8] = k0;
            *(f16x8*)&Ks[p ^ 1][(w * 2 + 1) * 512 + lane * 8] = k1;
            int cc0 = vc0 >> 3, c7 = vc0 & 7;
#pragma unroll
            for (int j = 0; j < 8; ++j) {
                Vt[p ^ 1][(vd0 + j) * 64 + ((cc0 ^ va ^ j) & 7) * 8 + c7] = v0[j];
                Vt[p ^ 1][(vd0 + j) * 64 + (((cc0 + 4) ^ va ^ j) & 7) * 8 + c7] = v1[j];
            }
        }
        __syncthreads();
    }

    // epilogue: write PACKED chunks. lane owns row = i0+w*16+r15 (row&15=r15),
    // cols col..col+3 with col = qoff + nd*16 + q4*4 (col%4==0, col&7 in {0,4}).
    float inv = 1.0f / l_l;
    const int KC2 = C >> 5;            // 24
    const int rc  = (i0 >> 4) + w;     // row-chunk
#pragma unroll
    for (int nd = 0; nd < 4; ++nd) {
        int col = qoff + nd * 16 + q4 * 4;
        int kc  = col >> 5;
        int lp  = r15 + ((col >> 3) & 3) * 16;
        f16x4 ov = { (f16)(o[nd][0] * inv), (f16)(o[nd][1] * inv),
                     (f16)(o[nd][2] * inv), (f16)(o[nd][3] * inv) };
        *(f16x4*)(outp + ((size_t)rc * KC2 + kc) * 512 + lp * 8 + (col & 7)) = ov;
    }
}

// ---------------------------------------------------------------------------
extern "C" void kernel_launch(void* const* d_in, const int* in_sizes, int n_in,
                              void* d_out, int out_size, void* d_ws, size_t ws_size,
                              hipStream_t stream) {
    (void)n_in; (void)out_size; (void)ws_size;
    const float* x      = (const float*)d_in[0];
    const float* qkv_w  = (const float*)d_in[1];
    const float* qkv_b  = (const float*)d_in[2];
    const float* proj_w = (const float*)d_in[3];
    const float* proj_b = (const float*)d_in[4];
    float* outp = (float*)d_out;

    const int C    = in_sizes[2] / 3;     // 768
    const int Nseq = in_sizes[0] / C;     // 4096
    const int C3   = 3 * C;               // 2304
    const int KC   = C >> 5;              // 24 k-chunks

    char* ws = (char*)d_ws;
    f16* qkv_h = (f16*)ws;   ws += (size_t)Nseq * C3 * 2;   // 18.9 MB (row-major)
    f16* xp    = (f16*)ws;   ws += (size_t)Nseq * C * 2;    // 6.3 MB packed (reused as attn_p)
    f16* wqp   = (f16*)ws;   ws += (size_t)C3 * C * 2;      // 3.5 MB packed
    f16* wpp   = (f16*)ws;                                   // 1.2 MB packed
    f16* attn_p = xp;   // alias: xp dead after GEMM1

    dim3 blk(256);
    {
        int nc0 = (Nseq / 16) * KC;   // x chunks      (6144)
        int nc1 = (C3 / 16) * KC;     // qkv_w chunks  (3456)
        int nc2 = (C / 16) * KC;      // proj_w chunks (1152)
        int nwaves = nc0 + nc1 + nc2;
        pack3_f32_f16<<<dim3((nwaves + 3) / 4), blk, 0, stream>>>(
            x, xp, nc0, KC, qkv_w, wqp, nc1, KC, proj_w, wpp, nc2, KC);
    }
    // qkv (f16 row-major) = x @ qkv_w^T + qkv_b   (128x128 tiles, 576 blocks)
    gemm_f16_packed<2, 2, 4, 4, f16><<<dim3(C3 / 128, Nseq / 128), blk, 0, stream>>>(
        xp, wqp, qkv_b, qkv_h, Nseq, C3, C);
    // banded attention -> packed f16
    local_attn_mfma<<<dim3((C / 64) * (Nseq / 64)), blk, 0, stream>>>(
        qkv_h, attn_p, Nseq);
    // out (f32) = attn @ proj_w^T + proj_b   (64x64 tiles, 768 blocks)
    gemm_f16_packed<2, 2, 2, 2, float><<<dim3(C / 64, Nseq / 64), blk, 0, stream>>>(
        attn_p, wpp, proj_b, outp, Nseq, C, C);
}

// Round 10
// 130.552 us; speedup vs baseline: 1.5181x; 1.0213x over previous
//
#include <hip/hip_runtime.h>
#include <hip/hip_fp16.h>
#include <cmath>

typedef _Float16 f16;
typedef __attribute__((ext_vector_type(8))) _Float16 f16x8;
typedef __attribute__((ext_vector_type(4))) _Float16 f16x4;
typedef __attribute__((ext_vector_type(4))) float f32x4;

#define EXP2F(x) __builtin_amdgcn_exp2f(x)

// ---------------------------------------------------------------------------
// Frag-linear packed layout: matrix [R,K] stored as chunks of 16 rows x 32 k
// = 512 f16 = 1 KB; chunk cid = (r>>4)*(K>>5) + (k>>5); lane
// l = (r&15) + ((k>>3)&3)*16 holds 8 f16 at l*8 — the mfma 16x16x32 operand
// fragment. Staging a chunk = ONE contiguous 1 KB wave load.
// ---------------------------------------------------------------------------
__global__ void pack3_f32_f16(
    const float* __restrict__ s0, f16* __restrict__ d0, int nc0, int kc0,
    const float* __restrict__ s1, f16* __restrict__ d1, int nc1, int kc1,
    const float* __restrict__ s2, f16* __restrict__ d2, int nc2, int kc2)
{
    int wid  = (blockIdx.x * blockDim.x + threadIdx.x) >> 6;
    int lane = threadIdx.x & 63;
    const float* s; f16* d; int cid, KC;
    if (wid < nc0)                  { s = s0; d = d0; cid = wid;             KC = kc0; }
    else if (wid < nc0 + nc1)       { s = s1; d = d1; cid = wid - nc0;       KC = kc1; }
    else if (wid < nc0 + nc1 + nc2) { s = s2; d = d2; cid = wid - nc0 - nc1; KC = kc2; }
    else return;
    int rc = cid / KC, kc = cid % KC;
    int K  = KC << 5;
    const float* src = s + (size_t)(rc * 16 + (lane & 15)) * K + kc * 32 + (lane >> 4) * 8;
    float4 v0 = *(const float4*)src;
    float4 v1 = *(const float4*)(src + 4);
    f16x8 o = { (f16)v0.x, (f16)v0.y, (f16)v0.z, (f16)v0.w,
                (f16)v1.x, (f16)v1.y, (f16)v1.z, (f16)v1.w };
    *(f16x8*)(d + (size_t)cid * 512 + lane * 8) = o;
}

__device__ __forceinline__ void store4(f16* p, const f32x4& v) {
    f16x4 o = { (f16)v[0], (f16)v[1], (f16)v[2], (f16)v[3] };
    *(f16x4*)p = o;
}
__device__ __forceinline__ void store4(float* p, const f32x4& v) {
    float4 o = { v[0], v[1], v[2], v[3] };
    *(float4*)p = o;
}

// ---------------------------------------------------------------------------
// Packed-operand MFMA GEMM (R9 pipeline). MODE 0: row-major OT output.
// MODE 1: qkv-special output — Q,K parts in per-head frag-linear chunks,
// V part written TRANSPOSED (V^T) in per-head frag-linear chunks, so the
// attention kernel loads every operand as a contiguous fragment.
//   Q/K elem (t,h,d):  tau*12*M*64 + h*M*64 + (t>>4)*1024 + (d>>5)*512
//                      + ((t&15)+((d>>3)&3)*16)*8 + (d&7)
//   V^T elem (d,t,h):  2*12*M*64 + h*M*64 + (d>>4)*(M*16) + (t>>5)*512
//                      + ((d&15)+((t>>3)&3)*16)*8 + (t&7)
// ---------------------------------------------------------------------------
template <int WR, int WC, int MT, int NT, int MODE, typename OT>
__global__ __launch_bounds__(256) void gemm_f16_packed(
    const f16* __restrict__ Ap,     // packed [M/16 * K/32] chunks
    const f16* __restrict__ Wp,     // packed [N/16 * K/32] chunks
    const float* __restrict__ bias, // [N]
    OT* __restrict__ out,
    int M, int N, int K)
{
    constexpr int KK  = 2;              // BK=64
    constexpr int ACH = WR * MT * KK;
    constexpr int BCH = WC * NT * KK;
    constexpr int AR  = ACH / 4;
    constexpr int BR  = BCH / 4;
    __shared__ f16 Ash[2][ACH * 512];
    __shared__ f16 Bsh[2][BCH * 512];

    const int tid  = threadIdx.x;
    const int lane = tid & 63;
    const int w    = tid >> 6;
    const int wr   = w / WC;
    const int wc   = w % WC;
    const int lr   = lane & 15;
    const int lq   = lane >> 4;
    const int bm   = blockIdx.y * (WR * MT * 16);
    const int bn   = blockIdx.x * (WC * NT * 16);
    const int KC   = K >> 5;

    const f16* ga[AR];
    const f16* gb[BR];
#pragma unroll
    for (int r = 0; r < AR; ++r) {
        int s = w * AR + r, rl = s / KK, kk = s % KK;
        ga[r] = Ap + ((size_t)((bm >> 4) + rl) * KC + kk) * 512 + lane * 8;
    }
#pragma unroll
    for (int r = 0; r < BR; ++r) {
        int s = w * BR + r, rl = s / KK, kk = s % KK;
        gb[r] = Wp + ((size_t)((bn >> 4) + rl) * KC + kk) * 512 + lane * 8;
    }

    f32x4 acc[MT][NT] = {};
    f16x8 sa[AR], sb[BR];

#pragma unroll
    for (int r = 0; r < AR; ++r) sa[r] = *(const f16x8*)(ga[r]);
#pragma unroll
    for (int r = 0; r < BR; ++r) sb[r] = *(const f16x8*)(gb[r]);
#pragma unroll
    for (int r = 0; r < AR; ++r) *(f16x8*)&Ash[0][(w * AR + r) * 512 + lane * 8] = sa[r];
#pragma unroll
    for (int r = 0; r < BR; ++r) *(f16x8*)&Bsh[0][(w * BR + r) * 512 + lane * 8] = sb[r];
    __syncthreads();

    const int nk = K >> 6;
    for (int k = 0; k < nk; ++k) {
        const int cur = k & 1;
        if (k + 1 < nk) {
            const int ko = (k + 1) * KK * 512;
#pragma unroll
            for (int r = 0; r < AR; ++r) sa[r] = *(const f16x8*)(ga[r] + ko);
#pragma unroll
            for (int r = 0; r < BR; ++r) sb[r] = *(const f16x8*)(gb[r] + ko);
        }
        f16x8 af[MT][KK], bf[NT][KK];
#pragma unroll
        for (int mt = 0; mt < MT; ++mt)
#pragma unroll
            for (int kk = 0; kk < KK; ++kk)
                af[mt][kk] = *(const f16x8*)&Ash[cur][((wr * MT + mt) * KK + kk) * 512 + lane * 8];
#pragma unroll
        for (int nt = 0; nt < NT; ++nt)
#pragma unroll
            for (int kk = 0; kk < KK; ++kk)
                bf[nt][kk] = *(const f16x8*)&Bsh[cur][((wc * NT + nt) * KK + kk) * 512 + lane * 8];
#pragma unroll
        for (int kk = 0; kk < KK; ++kk)
#pragma unroll
            for (int mt = 0; mt < MT; ++mt)
#pragma unroll
                for (int nt = 0; nt < NT; ++nt)
                    acc[mt][nt] = __builtin_amdgcn_mfma_f32_16x16x32_f16(
                        bf[nt][kk], af[mt][kk], acc[mt][nt], 0, 0, 0);
        if (k + 1 < nk) {
#pragma unroll
            for (int r = 0; r < AR; ++r)
                *(f16x8*)&Ash[cur ^ 1][(w * AR + r) * 512 + lane * 8] = sa[r];
#pragma unroll
            for (int r = 0; r < BR; ++r)
                *(f16x8*)&Bsh[cur ^ 1][(w * BR + r) * 512 + lane * 8] = sb[r];
        }
        __syncthreads();
    }

    // epilogue
#pragma unroll
    for (int mt = 0; mt < MT; ++mt) {
        int row = bm + (wr * MT + mt) * 16 + lr;
#pragma unroll
        for (int nt = 0; nt < NT; ++nt) {
            int col = bn + (wc * NT + nt) * 16 + lq * 4;
            float4 bv = *(const float4*)(bias + col);
            f32x4 ov = acc[mt][nt];
            ov[0] += bv.x; ov[1] += bv.y; ov[2] += bv.z; ov[3] += bv.w;
            if (MODE == 0) {
                store4(out + (size_t)row * N + col, ov);
            } else {
                // qkv layout: tau in {0:Q,1:K,2:V}, head hh, dim d
                int tau = (col >= 1536) ? 2 : (col >= 768 ? 1 : 0);
                int rm  = col - tau * 768;
                int hh  = rm >> 6;
                int d   = rm & 63;
                f16* base = (f16*)out + ((size_t)tau * 12 + hh) * ((size_t)M * 64);
                if (tau < 2) {
                    size_t off = (size_t)(row >> 4) * 1024 + (d >> 5) * 512
                               + (size_t)((row & 15) + ((d >> 3) & 3) * 16) * 8 + (d & 7);
                    store4(base + off, ov);
                } else {
                    // transposed scalar stores into V^T chunks
#pragma unroll
                    for (int i = 0; i < 4; ++i) {
                        int dd = d + i;
                        size_t off = (size_t)(dd >> 4) * ((size_t)M * 16)
                                   + (size_t)(row >> 5) * 512
                                   + (size_t)((dd & 15) + ((row >> 3) & 3) * 16) * 8 + (row & 7);
                        base[off] = (f16)ov[i];
                    }
                }
            }
        }
    }
}

// ---------------------------------------------------------------------------
// BARRIER-FREE MFMA local attention, window=128, hd=64.
// qkv in per-head frag-linear layout (Q, K chunks; V stored transposed):
// every MFMA operand is a direct contiguous 1 KB wave load — no staging LDS,
// no __syncthreads. Only LDS use: per-wave P round-trip (swizzled), ordered
// by lgkmcnt within the wave. Output written in packed chunks for GEMM2.
// LDS = 8 KB/block.
// ---------------------------------------------------------------------------
#define WINDOW_SZ 128

__global__ __launch_bounds__(256) void local_attn_mfma(
    const f16* __restrict__ qkvp,  // packed per-head Q | K | V^T
    f16* __restrict__ outp,        // packed [N/16 * C/32] chunks
    int N)
{
    const int C = 768;
    __shared__ f16 Ps[4096];       // 4 waves x 1024 f16

    const int tid  = threadIdx.x;
    const int lane = tid & 63;
    const int w    = tid >> 6;
    const int r15  = lane & 15;
    const int q4   = lane >> 4;
    const int ntiles = N >> 6;
    const int h  = blockIdx.x / ntiles;
    const int i0 = (blockIdx.x % ntiles) << 6;

    const size_t hstride = (size_t)N * 64;
    const f16* Qh = qkvp + (size_t)h * hstride;
    const f16* Kh = qkvp + (size_t)(12 + h) * hstride;
    const f16* Vh = qkvp + (size_t)(24 + h) * hstride;
    const int dcStride = N * 16;   // V^T d-chunk stride

    // Q frags (loop-invariant), prescaled by 0.125*log2(e)
    f16x8 qf[2];
    {
        const f16* qp = Qh + (size_t)((i0 >> 4) + w) * 1024 + lane * 8;
        qf[0] = *(const f16x8*)(qp);
        qf[1] = *(const f16x8*)(qp + 512);
        const f16 qs = (f16)0.18033688f;
#pragma unroll
        for (int j = 0; j < 8; ++j) { qf[0][j] *= qs; qf[1][j] *= qs; }
    }

    f32x4 o[4] = {};
    float m_l = -1.0e30f, l_l = 0.f;

    const int lo = (i0 >= 128) ? 0 : ((128 - i0) >> 6);
    int hi = (N + 64 - i0) >> 6; if (hi > 4) hi = 4;

    const int lssr = lane ^ ((lane >> 3) & 7);

    for (int ch = lo; ch <= hi; ++ch) {
        const int jbase = i0 - 128 + ch * 64;
        const bool need_mask = (ch == 0) || (ch == 4);

        // S^T = K @ Q^T : direct contiguous K frag loads
        f32x4 s[4] = {};
#pragma unroll
        for (int ks = 0; ks < 2; ++ks)
#pragma unroll
            for (int nt = 0; nt < 4; ++nt) {
                f16x8 kf = *(const f16x8*)(Kh + (size_t)((jbase >> 4) + nt) * 1024
                                              + ks * 512 + lane * 8);
                s[nt] = __builtin_amdgcn_mfma_f32_16x16x32_f16(kf, qf[ks], s[nt], 0, 0, 0);
            }

        if (need_mask) {
            int qg = i0 + w * 16 + r15;
#pragma unroll
            for (int nt = 0; nt < 4; ++nt)
#pragma unroll
                for (int r = 0; r < 4; ++r) {
                    int dist = qg - (jbase + nt * 16 + q4 * 4 + r);
                    if (dist < 0) dist = -dist;
                    if (dist > WINDOW_SZ) s[nt][r] = -3.0e38f;
                }
        }

        // online softmax (exp2 domain); lane owns q-row r15
        float rmax = -3.0e38f;
#pragma unroll
        for (int nt = 0; nt < 4; ++nt)
#pragma unroll
            for (int r = 0; r < 4; ++r) rmax = fmaxf(rmax, s[nt][r]);
        rmax = fmaxf(rmax, __shfl_xor(rmax, 16));
        rmax = fmaxf(rmax, __shfl_xor(rmax, 32));
        float mn = fmaxf(m_l, rmax);
        float al = EXP2F(m_l - mn);
        m_l = mn;
        float rs = 0.f;
#pragma unroll
        for (int nt = 0; nt < 4; ++nt)
#pragma unroll
            for (int r = 0; r < 4; ++r) {
                float pv = EXP2F(s[nt][r] - mn);
                s[nt][r] = pv;
                rs += pv;
            }
        rs += __shfl_xor(rs, 16);
        rs += __shfl_xor(rs, 32);
        l_l = l_l * al + rs;
#pragma unroll
        for (int nd = 0; nd < 4; ++nd)
#pragma unroll
            for (int r = 0; r < 4; ++r) o[nd][r] *= al;

        // P -> Ps (per-wave, swizzled B-frag layout; no barrier)
#pragma unroll
        for (int nt = 0; nt < 4; ++nt)
#pragma unroll
            for (int r = 0; r < 4; ++r) {
                int c  = nt * 16 + q4 * 4 + r;
                int cs = c >> 5;
                int c5 = c & 31;
                int ls = (c5 >> 3) * 16 + r15;
                int lss = ls ^ ((ls >> 3) & 7);
                Ps[(w * 2 + cs) * 512 + lss * 8 + (c5 & 7)] = (f16)s[nt][r];
            }

        // O^T += V^T @ P^T : direct contiguous V^T frag loads
#pragma unroll
        for (int cs = 0; cs < 2; ++cs) {
            f16x8 pf = *(const f16x8*)&Ps[(w * 2 + cs) * 512 + lssr * 8];
#pragma unroll
            for (int nd = 0; nd < 4; ++nd) {
                f16x8 vf = *(const f16x8*)(Vh + (size_t)nd * dcStride
                                              + (size_t)((jbase >> 5) + cs) * 512 + lane * 8);
                o[nd] = __builtin_amdgcn_mfma_f32_16x16x32_f16(vf, pf, o[nd], 0, 0, 0);
            }
        }
    }

    // epilogue: packed chunks for GEMM2 (lane owns q-row r15, 4 consecutive d)
    float inv = 1.0f / l_l;
    const int KC2 = C >> 5;
    const int rc  = (i0 >> 4) + w;
#pragma unroll
    for (int nd = 0; nd < 4; ++nd) {
        int col = h * 64 + nd * 16 + q4 * 4;
        int kc  = col >> 5;
        int lp  = r15 + ((col >> 3) & 3) * 16;
        f16x4 ov = { (f16)(o[nd][0] * inv), (f16)(o[nd][1] * inv),
                     (f16)(o[nd][2] * inv), (f16)(o[nd][3] * inv) };
        *(f16x4*)(outp + ((size_t)rc * KC2 + kc) * 512 + lp * 8 + (col & 7)) = ov;
    }
}

// ---------------------------------------------------------------------------
extern "C" void kernel_launch(void* const* d_in, const int* in_sizes, int n_in,
                              void* d_out, int out_size, void* d_ws, size_t ws_size,
                              hipStream_t stream) {
    (void)n_in; (void)out_size; (void)ws_size;
    const float* x      = (const float*)d_in[0];
    const float* qkv_w  = (const float*)d_in[1];
    const float* qkv_b  = (const float*)d_in[2];
    const float* proj_w = (const float*)d_in[3];
    const float* proj_b = (const float*)d_in[4];
    float* outp = (float*)d_out;

    const int C    = in_sizes[2] / 3;     // 768
    const int Nseq = in_sizes[0] / C;     // 4096
    const int C3   = 3 * C;               // 2304
    const int KC   = C >> 5;              // 24

    char* ws = (char*)d_ws;
    f16* qkv_p = (f16*)ws;   ws += (size_t)Nseq * C3 * 2;   // 18.9 MB per-head packed
    f16* xp    = (f16*)ws;   ws += (size_t)Nseq * C * 2;    // 6.3 MB packed (reused as attn_p)
    f16* wqp   = (f16*)ws;   ws += (size_t)C3 * C * 2;      // 3.5 MB packed
    f16* wpp   = (f16*)ws;                                   // 1.2 MB packed
    f16* attn_p = xp;   // alias: xp dead after GEMM1

    dim3 blk(256);
    {
        int nc0 = (Nseq / 16) * KC;
        int nc1 = (C3 / 16) * KC;
        int nc2 = (C / 16) * KC;
        int nwaves = nc0 + nc1 + nc2;
        pack3_f32_f16<<<dim3((nwaves + 3) / 4), blk, 0, stream>>>(
            x, xp, nc0, KC, qkv_w, wqp, nc1, KC, proj_w, wpp, nc2, KC);
    }
    // qkv (per-head packed; V transposed) = x @ qkv_w^T + qkv_b
    gemm_f16_packed<2, 2, 4, 4, 1, f16><<<dim3(C3 / 128, Nseq / 128), blk, 0, stream>>>(
        xp, wqp, qkv_b, qkv_p, Nseq, C3, C);
    // barrier-free banded attention -> packed f16
    local_attn_mfma<<<dim3((C / 64) * (Nseq / 64)), blk, 0, stream>>>(
        qkv_p, attn_p, Nseq);
    // out (f32 row-major) = attn @ proj_w^T + proj_b
    gemm_f16_packed<2, 2, 2, 2, 0, float><<<dim3(C / 64, Nseq / 64), blk, 0, stream>>>(
        attn_p, wpp, proj_b, outp, Nseq, C, C);
}